// Round 8
// baseline (15425.197 us; speedup 1.0000x reference)
//
#include <hip/hip_runtime.h>
#include <stdint.h>

#define TSTEPS 8192
#define HDIM 512

typedef unsigned long long ull;

// ---------------------------------------------------------------------------
__device__ __forceinline__ ull pack_th(unsigned tag, float v) {
    union { float f; unsigned u; } x; x.f = v;
    return ((ull)tag << 32) | (ull)x.u;
}
__device__ __forceinline__ float unpack_v(ull p) {
    union { unsigned u; float f; } x; x.u = (unsigned)p;
    return x.f;
}

// ---------------------------------------------------------------------------
// Fused 2-layer persistent LSTM, register-distributed, wave-autonomous.
// 256 WGs x 256 threads = 1 WG/CU; wave = one hidden unit j.
//   blocks   0..127: layer 1 (j = wb*4+wave).   feed = x(t) (global loads)
//   blocks 128..255: layer 2.                    feed = h1(t) (ring0 poll)
// Lane l holds W[r][l+64u] for r=0..3 (gate rows of j), u=0..7:
//   32 weights/matrix, 64 total per thread.
// No __shared__, no __syncthreads: h polled straight into registers from
// {tag,value} 8B ring slots; 6-level shfl_xor butterfly x4 accumulators
// gives every lane all 4 gate sums (~150ns compute per step).
//
// amdgpu_waves_per_eu(1,1) is THE fix for R3/R5: it sets the allocator's
// occupancy target to 1 wave/EU -> full 512-VGPR budget, so the 64 weight
// floats + working set (~130 VGPRs) stay register-resident instead of
// spilling to scratch (R5: VGPR=64, 148MB scratch writes, 2x slowdown).
// Grid 256 WGs <= 256 CUs keeps the spin protocol co-resident regardless.
//
// ring0/ring1 are FULL-HISTORY (slot s = state after s steps, tag s+1;
// written once -> L1 never waits for L2, no back-pressure).
// Tags <= 8194: poison 0xAAAAAAAA / 0x00000000 never match.
// ---------------------------------------------------------------------------
__global__ __attribute__((amdgpu_waves_per_eu(1, 1))) __launch_bounds__(256)
void lstm_fused(
    const float* __restrict__ x,      // [T][512]
    const float* __restrict__ Whh0,   // [2048][512]
    const float* __restrict__ Wih0,   // [2048][512]
    const float* __restrict__ bih0,   // [2048]
    const float* __restrict__ bhh0,   // [2048]
    const float* __restrict__ Wih1,   // [2048][512]
    const float* __restrict__ Whh1,   // [2048][512]
    const float* __restrict__ bih1,   // [2048]
    const float* __restrict__ bhh1,   // [2048]
    const float* __restrict__ h0,     // [2][512]
    const float* __restrict__ c0,     // [2][512]
    float* __restrict__ h2seq,        // [T][512]
    ull* __restrict__ ring0,          // [T+2][512]
    ull* __restrict__ ring1)          // [T+2][512]
{
    const int L2   = (blockIdx.x >= 128) ? 1 : 0;
    const int wb   = L2 ? (int)blockIdx.x - 128 : (int)blockIdx.x;
    const int tid  = threadIdx.x;
    const int wave = tid >> 6;
    const int lane = tid & 63;
    const int j    = wb * 4 + wave;

    // ---- register-resident weights: wA = recurrent, wB = feed -------------
    float wA[4][8], wB[4][8];
    {
        const float* WA = L2 ? Whh1 : Whh0;
        const float* WB = L2 ? Wih1 : Wih0;
#pragma unroll
        for (int r = 0; r < 4; ++r) {
            const size_t rb = (size_t)(r * HDIM + j) * HDIM + lane;
#pragma unroll
            for (int u = 0; u < 8; ++u) {
                wA[r][u] = WA[rb + 64 * u];
                wB[r][u] = WB[rb + 64 * u];
            }
        }
    }
    float bb[4];
#pragma unroll
    for (int r = 0; r < 4; ++r)
        bb[r] = L2 ? (bih1[r * HDIM + j] + bhh1[r * HDIM + j])
                   : (bih0[r * HDIM + j] + bhh0[r * HDIM + j]);
    float c = c0[(L2 ? HDIM : 0) + j];

    ull* rring = L2 ? ring1 : ring0;   // recurrent (self) ring

    // initial state -> slot 0, tag 1 (one publisher per j)
    if (lane == 0)
        __hip_atomic_store(&rring[j], pack_th(1u, h0[(L2 ? HDIM : 0) + j]),
                           __ATOMIC_RELAXED, __HIP_MEMORY_SCOPE_AGENT);

    // ---- feed(0) into registers -------------------------------------------
    float fv[8];
    if (!L2) {
#pragma unroll
        for (int u = 0; u < 8; ++u) fv[u] = x[lane + 64 * u];
    } else {
        const ull* s = ring0 + (size_t)1 * HDIM + lane;   // h1(0) = slot 1
        ull p[8]; bool ok;
        do {
            ok = true;
#pragma unroll
            for (int u = 0; u < 8; ++u)
                p[u] = __hip_atomic_load(&s[64 * u], __ATOMIC_RELAXED, __HIP_MEMORY_SCOPE_AGENT);
#pragma unroll
            for (int u = 0; u < 8; ++u) ok &= ((unsigned)(p[u] >> 32) == 2u);
            if (!ok) __builtin_amdgcn_s_sleep(1);
        } while (!ok);
#pragma unroll
        for (int u = 0; u < 8; ++u) fv[u] = unpack_v(p[u]);
    }

    for (int t = 0; t < TSTEPS; ++t) {
        // ---- recurrent poll straight into registers (critical path) -------
        float hv[8];
        {
            const ull* s = rring + (size_t)t * HDIM + lane;
            const unsigned tg = (unsigned)(t + 1);
            ull p[8]; bool ok;
            do {
                ok = true;
#pragma unroll
                for (int u = 0; u < 8; ++u)
                    p[u] = __hip_atomic_load(&s[64 * u], __ATOMIC_RELAXED, __HIP_MEMORY_SCOPE_AGENT);
#pragma unroll
                for (int u = 0; u < 8; ++u) ok &= ((unsigned)(p[u] >> 32) == tg);
                if (!ok) __builtin_amdgcn_s_sleep(1);
            } while (!ok);
#pragma unroll
            for (int u = 0; u < 8; ++u) hv[u] = unpack_v(p[u]);
        }

        // ---- 4-row partial dot (recurrent + feed) -------------------------
        float a0 = 0.f, a1 = 0.f, a2 = 0.f, a3 = 0.f;
#pragma unroll
        for (int u = 0; u < 8; ++u) {
            a0 += wA[0][u] * hv[u]; a1 += wA[1][u] * hv[u];
            a2 += wA[2][u] * hv[u]; a3 += wA[3][u] * hv[u];
        }
#pragma unroll
        for (int u = 0; u < 8; ++u) {
            a0 += wB[0][u] * fv[u]; a1 += wB[1][u] * fv[u];
            a2 += wB[2][u] * fv[u]; a3 += wB[3][u] * fv[u];
        }

        // ---- wave butterfly: every lane gets all 4 gate sums --------------
#pragma unroll
        for (int m = 1; m < 64; m <<= 1) {
            a0 += __shfl_xor(a0, m);
            a1 += __shfl_xor(a1, m);
            a2 += __shfl_xor(a2, m);
            a3 += __shfl_xor(a3, m);
        }

        const float iv = 1.f / (1.f + __expf(-(a0 + bb[0])));
        const float ff = 1.f / (1.f + __expf(-(a1 + bb[1])));
        const float gg = 1.f - 2.f / (__expf(2.f * (a2 + bb[2])) + 1.f);
        const float ov = 1.f / (1.f + __expf(-(a3 + bb[3])));
        c = ff * c + iv * gg;
        const float h = ov * (1.f - 2.f / (__expf(2.f * c) + 1.f));

        // ---- publish (lane 0); h2seq store off-path (lane 1) --------------
        if (lane == 0)
            __hip_atomic_store(&rring[(size_t)(t + 1) * HDIM + j],
                               pack_th((unsigned)(t + 2), h),
                               __ATOMIC_RELAXED, __HIP_MEMORY_SCOPE_AGENT);
        if (L2 && lane == 1)
            h2seq[(size_t)t * HDIM + j] = h;

        // ---- feed(t+1) (off critical path; L1 runs ahead of L2) -----------
        if (t + 1 < TSTEPS) {
            if (!L2) {
#pragma unroll
                for (int u = 0; u < 8; ++u)
                    fv[u] = x[(size_t)(t + 1) * HDIM + lane + 64 * u];
            } else {
                const ull* s = ring0 + (size_t)(t + 2) * HDIM + lane;  // h1(t+1)
                const unsigned tg = (unsigned)(t + 3);
                ull p[8]; bool ok;
                do {
                    ok = true;
#pragma unroll
                    for (int u = 0; u < 8; ++u)
                        p[u] = __hip_atomic_load(&s[64 * u], __ATOMIC_RELAXED, __HIP_MEMORY_SCOPE_AGENT);
#pragma unroll
                    for (int u = 0; u < 8; ++u) ok &= ((unsigned)(p[u] >> 32) == tg);
                    if (!ok) __builtin_amdgcn_s_sleep(1);
                } while (!ok);
#pragma unroll
                for (int u = 0; u < 8; ++u) fv[u] = unpack_v(p[u]);
            }
        }
    }
}

// ---------------------------------------------------------------------------
// Head + BCE loss.
// ---------------------------------------------------------------------------
__global__ __launch_bounds__(256) void head_loss(
    const float* __restrict__ h2,   // [T][512]
    const float* __restrict__ Wh,   // [2][512]
    const float* __restrict__ bh,   // [2]
    const float* __restrict__ y,    // [T][2]
    float* __restrict__ out)
{
    const int tid  = threadIdx.x;
    const int lane = tid & 63;
    const int wv   = tid >> 6;
    const int gw   = blockIdx.x * 4 + wv;   // 0..1023

    float w0[8], w1[8];
#pragma unroll
    for (int u = 0; u < 8; ++u) {
        w0[u] = Wh[lane * 8 + u];
        w1[u] = Wh[HDIM + lane * 8 + u];
    }

    float lsum = 0.f;
    for (int t = gw; t < TSTEPS; t += 1024) {
        const float* hp = h2 + (size_t)t * HDIM + lane * 8;
        float4 hv0 = *(const float4*)&hp[0];
        float4 hv1 = *(const float4*)&hp[4];
        float a0 = hv0.x * w0[0] + hv0.y * w0[1] + hv0.z * w0[2] + hv0.w * w0[3]
                 + hv1.x * w0[4] + hv1.y * w0[5] + hv1.z * w0[6] + hv1.w * w0[7];
        float a1 = hv0.x * w1[0] + hv0.y * w1[1] + hv0.z * w1[2] + hv0.w * w1[3]
                 + hv1.x * w1[4] + hv1.y * w1[5] + hv1.z * w1[6] + hv1.w * w1[7];
#pragma unroll
        for (int m = 1; m < 64; m <<= 1) {
            a0 += __shfl_xor(a0, m);
            a1 += __shfl_xor(a1, m);
        }
        if (lane == 0) {
            const float z0 = a0 + bh[0];
            const float z1 = a1 + bh[1];
            const float p0 = 1.f / (1.f + __expf(-z0));
            const float p1 = 1.f / (1.f + __expf(-z1));
            const float lp0  = fmaxf(__logf(p0), -100.f);
            const float lp1  = fmaxf(__logf(p1), -100.f);
            const float l1p0 = fmaxf(log1pf(-p0), -100.f);
            const float l1p1 = fmaxf(log1pf(-p1), -100.f);
            const float y0 = y[(size_t)t * 2 + 0];
            const float y1 = y[(size_t)t * 2 + 1];
            lsum += y0 * lp0 + (1.f - y0) * l1p0;
            lsum += y1 * lp1 + (1.f - y1) * l1p1;
        }
    }

    __shared__ float red[4];
    if (lane == 0) red[wv] = lsum;
    __syncthreads();
    if (tid == 0) {
        const float ssum = red[0] + red[1] + red[2] + red[3];
        atomicAdd(out, ssum * (-1.f / (float)(TSTEPS * 2)));
    }
}

// ---------------------------------------------------------------------------
extern "C" void kernel_launch(void* const* d_in, const int* in_sizes, int n_in,
                              void* d_out, int out_size, void* d_ws, size_t ws_size,
                              hipStream_t stream)
{
    const float* x     = (const float*)d_in[0];   // [8192][1][512]
    const float* truth = (const float*)d_in[1];   // [8192][1][2]
    const float* h0    = (const float*)d_in[2];   // [2][1][512]
    const float* c0    = (const float*)d_in[3];   // [2][1][512]
    const float* Wih0  = (const float*)d_in[4];
    const float* Whh0  = (const float*)d_in[5];
    const float* bih0  = (const float*)d_in[6];
    const float* bhh0  = (const float*)d_in[7];
    const float* Wih1  = (const float*)d_in[8];
    const float* Whh1  = (const float*)d_in[9];
    const float* bih1  = (const float*)d_in[10];
    const float* bhh1  = (const float*)d_in[11];
    const float* Whead = (const float*)d_in[12];
    const float* bhead = (const float*)d_in[13];

    char* ws = (char*)d_ws;
    ull*   ring0 = (ull*)ws;                               // 33.6 MB [8194][512]
    ull*   ring1 = (ull*)(ws + (((size_t)34) << 20));      // 33.6 MB [8194][512]
    float* h2seq = (float*)(ws + (((size_t)68) << 20));    // 16 MB  [T][512]

    hipMemsetAsync(d_out, 0, (size_t)out_size * sizeof(float), stream);

    lstm_fused<<<256, 256, 0, stream>>>(x, Whh0, Wih0, bih0, bhh0,
                                        Wih1, Whh1, bih1, bhh1,
                                        h0, c0, h2seq, ring0, ring1);
    head_loss<<<256, 256, 0, stream>>>(h2seq, Whead, bhead, truth, (float*)d_out);
}